// Round 1
// baseline (6875.938 us; speedup 1.0000x reference)
//
#include <hip/hip_runtime.h>
#include <hip/hip_bf16.h>

// DelayRNN on MI355X.
// Design: persistent 32-WG kernel, each WG owns a 16-column slice of the hidden
// dim. Weights stay L1/L2-resident (read as bf16 MFMA B-frags each K-step),
// delay buffer lives in LDS (owner-exclusive), only h-vectors (32KB bf16)
// round-trip global memory between grid barriers. 3 barriers per step.

constexpr int kB    = 32;    // batch
constexpr int kS    = 256;   // encode steps
constexpr int kI    = 128;   // input dim
constexpr int kH    = 512;   // hidden
constexpr int kC    = 64;    // output channels
constexpr int kOutL = 64;    // decode steps
constexpr int kMaxD = 16;
constexpr int kBufD = 17;
constexpr int kNWG  = 32;    // workgroups (each owns kH/kNWG = 16 hidden cols)
constexpr int kJPW  = 16;    // hidden cols per WG
constexpr int kSteps = kS + kOutL;  // 320

typedef __bf16 bf16x8 __attribute__((ext_vector_type(8)));
typedef float  f32x4  __attribute__((ext_vector_type(4)));

__device__ __forceinline__ bf16x8 ld8(const __hip_bfloat16* p) {
  return *reinterpret_cast<const bf16x8*>(p);
}
__device__ __forceinline__ bf16x8 zero8() {
  bf16x8 r;
  uint32_t z[4] = {0u, 0u, 0u, 0u};
  __builtin_memcpy(&r, z, 16);
  return r;
}
__device__ __forceinline__ float sigm(float x) { return 1.0f / (1.0f + __expf(-x)); }

// Generation-numbered grid barrier. Flags zeroed by hipMemsetAsync each launch;
// gen is strictly increasing (1..960). Relaxed atomic spins (agent-scope atomics
// are serviced at the coherence point, no per-poll cache invalidation), explicit
// release fence before arrival, acquire fence after departure.
__device__ __forceinline__ void gbar(int* arrive, int* release, int wg, int gen) {
  __syncthreads();
  if (threadIdx.x == 0) {
    __builtin_amdgcn_fence(__ATOMIC_RELEASE, "agent");
    __hip_atomic_store(&arrive[wg * 64], gen, __ATOMIC_RELAXED, __HIP_MEMORY_SCOPE_AGENT);
  }
  if (wg == 0) {
    if (threadIdx.x < kNWG) {
      while (__hip_atomic_load(&arrive[threadIdx.x * 64], __ATOMIC_RELAXED,
                               __HIP_MEMORY_SCOPE_AGENT) < gen)
        __builtin_amdgcn_s_sleep(1);
    }
    __syncthreads();
    if (threadIdx.x == 0) {
      __builtin_amdgcn_fence(__ATOMIC_RELEASE, "agent");
      __hip_atomic_store(release, gen, __ATOMIC_RELAXED, __HIP_MEMORY_SCOPE_AGENT);
    }
  } else {
    if (threadIdx.x == 0) {
      while (__hip_atomic_load(release, __ATOMIC_RELAXED, __HIP_MEMORY_SCOPE_AGENT) < gen)
        __builtin_amdgcn_s_sleep(1);
    }
  }
  __syncthreads();
  __builtin_amdgcn_fence(__ATOMIC_ACQUIRE, "agent");
}

// Transpose weights to [col][k] bf16 (so MFMA B-fragments are 16B-contiguous
// loads) and cast x to bf16.
__global__ void prep(const float* x, const float* W_in, const float* W_pass,
                     const float* W_tau, const float* W_mem, const float* W_out,
                     __hip_bfloat16* xb, __hip_bfloat16* WtIn, __hip_bfloat16* WtPass,
                     __hip_bfloat16* WtTau, __hip_bfloat16* WtMem, __hip_bfloat16* WtOut) {
  const int tid = blockIdx.x * blockDim.x + threadIdx.x;
  const int nth = gridDim.x * blockDim.x;
  for (int i = tid; i < kB * kS * kI; i += nth) xb[i] = __float2bfloat16(x[i]);
  for (int i = tid; i < kH * (kH + kI); i += nth) {
    int j = i / (kH + kI), k = i - j * (kH + kI);
    WtIn[i] = __float2bfloat16(W_in[k * kH + j]);
  }
  for (int i = tid; i < kH * kH; i += nth) {
    int j = i >> 9, k = i & 511;
    WtPass[i] = __float2bfloat16(W_pass[k * kH + j]);
    WtTau[i]  = __float2bfloat16(W_tau[k * kH + j]);
    WtMem[i]  = __float2bfloat16(W_mem[k * kH + j]);
  }
  for (int i = tid; i < kC * kH; i += nth) {
    int c = i >> 9, j = i & 511;
    WtOut[i] = __float2bfloat16(W_out[j * kC + c]);
  }
}

struct KParams {
  const __hip_bfloat16* xb;
  const __hip_bfloat16* WtIn;
  const __hip_bfloat16* WtPass;
  const __hip_bfloat16* WtTau;
  const __hip_bfloat16* WtMem;
  const __hip_bfloat16* WtOut;
  __hip_bfloat16* h0g;   // [kB][kH] current buffer[:,:,0], bf16
  __hip_bfloat16* hpg;   // [kB][kH] h_pre
  __hip_bfloat16* hg;    // [kB][kH] blended h
  int* arrive;
  int* release;
  const int* lengths;
  const float* b_in;
  const float* b_pass;
  const float* b_tau;
  const float* b_mem;
  const float* b_out;
  float* dout;           // [kB][kOutL][kC]
};

__global__ __launch_bounds__(256) void rnn_main(KParams P) {
  __shared__ float buf[kB][kJPW][kBufD];   // delay buffer, fp32, owner-exclusive
  __shared__ float gpart[2][kB][33];       // K-half partial C tiles (+pad col)
  __shared__ float hpre_own[kB][kJPW];     // fp32 h_pre for owned cols
  __shared__ float h_own[kB][kJPW];        // fp32 blended h for owned cols
  __shared__ int   len_s[kB];

  const int wg   = blockIdx.x;
  const int tid  = threadIdx.x;
  const int lane = tid & 63;
  const int wave = tid >> 6;       // 4 waves: (mt, kh)
  const int mt   = wave & 1;       // which 16 batch rows
  const int kh   = wave >> 1;      // which K half
  const int row  = mt * 16 + (lane & 15);          // A-frag batch row
  const int kq   = (lane >> 4) * 8;                // A/B-frag k sub-offset
  const int jcol = wg * kJPW + (lane & 15);        // B-frag owned hidden col

  for (int i = tid; i < kB * kJPW * kBufD; i += 256) (&buf[0][0][0])[i] = 0.0f;
  if (tid < kB) len_s[tid] = P.lengths[tid];
  __syncthreads();

  int gen = 0;
  for (int t = 0; t < kSteps; ++t) {
    const bool dec = (t >= kS);

    // ---- decode output GEMV: out = h0 @ W_out + b_out (pre-update h0) ----
    if (dec) {
      const int cl = tid >> 7;          // 2 cols per WG
      const int b  = (tid >> 2) & 31;
      const int q  = tid & 3;           // 4-way K split
      const int c  = wg * 2 + cl;
      const __hip_bfloat16* hrow = P.h0g + b * kH;
      const __hip_bfloat16* wrow = P.WtOut + c * kH;
      float s = 0.f;
      for (int j = q * 128; j < q * 128 + 128; j += 8) {
#pragma unroll
        for (int u = 0; u < 8; ++u)
          s += __bfloat162float(hrow[j + u]) * __bfloat162float(wrow[j + u]);
      }
      s += __shfl_xor(s, 1);
      s += __shfl_xor(s, 2);
      if (q == 0) P.dout[b * (kOutL * kC) + (t - kS) * kC + c] = s + P.b_out[c];
    }

    // ---- Phase A: h_pre = [h0, x_t] @ W_in + b_in   (K = 640) ----
    {
      f32x4 acc = {0.f, 0.f, 0.f, 0.f};
#pragma unroll
      for (int i = 0; i < 10; ++i) {
        const int kk = kh * 320 + i * 32 + kq;
        bf16x8 a;
        if (kk < kH) a = ld8(P.h0g + row * kH + kk);
        else         a = dec ? zero8() : ld8(P.xb + (row * kS + t) * kI + (kk - kH));
        bf16x8 bb = ld8(P.WtIn + jcol * (kH + kI) + kk);
        acc = __builtin_amdgcn_mfma_f32_16x16x32_bf16(a, bb, acc, 0, 0, 0);
      }
#pragma unroll
      for (int r = 0; r < 4; ++r)
        gpart[kh][mt * 16 + (lane >> 4) * 4 + r][lane & 15] = acc[r];
    }
    __syncthreads();
    for (int it = tid; it < kB * kJPW; it += 256) {
      const int b = it >> 4, jl = it & 15;
      const int j = wg * kJPW + jl;
      float v = gpart[0][b][jl] + gpart[1][b][jl] + P.b_in[j];
      hpre_own[b][jl] = v;
      P.hpg[b * kH + j] = __float2bfloat16(v);
    }
    ++gen; gbar(P.arrive, P.release, wg, gen);

    // ---- Phase B: p = h_pre @ W_pass + b_pass; h = m*p + (1-m)*h_pre ----
    {
      f32x4 acc = {0.f, 0.f, 0.f, 0.f};
#pragma unroll
      for (int i = 0; i < 8; ++i) {
        const int kk = kh * 256 + i * 32 + kq;
        bf16x8 a  = ld8(P.hpg + row * kH + kk);
        bf16x8 bb = ld8(P.WtPass + jcol * kH + kk);
        acc = __builtin_amdgcn_mfma_f32_16x16x32_bf16(a, bb, acc, 0, 0, 0);
      }
#pragma unroll
      for (int r = 0; r < 4; ++r)
        gpart[kh][mt * 16 + (lane >> 4) * 4 + r][lane & 15] = acc[r];
    }
    __syncthreads();
    for (int it = tid; it < kB * kJPW; it += 256) {
      const int b = it >> 4, jl = it & 15;
      const int j = wg * kJPW + jl;
      float p = gpart[0][b][jl] + gpart[1][b][jl] + P.b_pass[j];
      // mask: encode m = (t < len[b]); decode m = 1 (exact binary blend)
      float hv = (t >= kS || t < len_s[b]) ? p : hpre_own[b][jl];
      h_own[b][jl] = hv;
      P.hg[b * kH + j] = __float2bfloat16(hv);
    }
    ++gen; gbar(P.arrive, P.release, wg, gen);

    // ---- Phase C: tau/mem GEMMs + delay-buffer update ----
    {
      f32x4 acc0 = {0.f, 0.f, 0.f, 0.f};
      f32x4 acc1 = {0.f, 0.f, 0.f, 0.f};
#pragma unroll
      for (int i = 0; i < 8; ++i) {
        const int kk = kh * 256 + i * 32 + kq;
        bf16x8 a  = ld8(P.hg + row * kH + kk);
        bf16x8 bt = ld8(P.WtTau + jcol * kH + kk);
        bf16x8 bm = ld8(P.WtMem + jcol * kH + kk);
        acc0 = __builtin_amdgcn_mfma_f32_16x16x32_bf16(a, bt, acc0, 0, 0, 0);
        acc1 = __builtin_amdgcn_mfma_f32_16x16x32_bf16(a, bm, acc1, 0, 0, 0);
      }
#pragma unroll
      for (int r = 0; r < 4; ++r) {
        const int br = mt * 16 + (lane >> 4) * 4 + r;
        gpart[kh][br][lane & 15]        = acc0[r];
        gpart[kh][br][16 + (lane & 15)] = acc1[r];
      }
    }
    __syncthreads();
    for (int it = tid; it < kB * kJPW; it += 256) {
      const int b = it >> 4, jl = it & 15;
      const int j = wg * kJPW + jl;
      float gt = gpart[0][b][jl]      + gpart[1][b][jl]      + P.b_tau[j];
      float gm = gpart[0][b][16 + jl] + gpart[1][b][16 + jl] + P.b_mem[j];
      float tau = 16.0f * sigm(gt);
      tau = fminf(fmaxf(tau, 1.0f), 16.0f);
      float ml = sigm(gm);
      float hv = h_own[b][jl];
      float* bp = buf[b][jl];
#pragma unroll
      for (int d = 1; d <= kMaxD; ++d) {
        float w = ml / (1.0f + fabsf(tau - (float)d));
        bp[d - 1] = bp[d] + w * hv;     // shift-left + weighted write
      }
      bp[kMaxD] = 0.0f;
      P.h0g[b * kH + j] = __float2bfloat16(bp[0]);
    }
    ++gen; gbar(P.arrive, P.release, wg, gen);
  }
}

extern "C" void kernel_launch(void* const* d_in, const int* in_sizes, int n_in,
                              void* d_out, int out_size, void* d_ws, size_t ws_size,
                              hipStream_t stream) {
  const float* x      = (const float*)d_in[0];
  const int*   lens   = (const int*)d_in[1];
  const float* W_in   = (const float*)d_in[3];
  const float* b_in   = (const float*)d_in[4];
  const float* W_pass = (const float*)d_in[5];
  const float* b_pass = (const float*)d_in[6];
  const float* W_tau  = (const float*)d_in[7];
  const float* b_tau  = (const float*)d_in[8];
  const float* W_mem  = (const float*)d_in[9];
  const float* b_mem  = (const float*)d_in[10];
  const float* W_out  = (const float*)d_in[11];
  const float* b_out  = (const float*)d_in[12];

  char* ws = (char*)d_ws;
  size_t off = 0;
  int* arrive  = (int*)(ws + off); off += 32 * 64 * sizeof(int);        // 8192
  int* release = (int*)(ws + off); off += 256;                           // 8448
  __hip_bfloat16* h0g = (__hip_bfloat16*)(ws + off); off += (size_t)kB * kH * 2;
  __hip_bfloat16* hpg = (__hip_bfloat16*)(ws + off); off += (size_t)kB * kH * 2;
  __hip_bfloat16* hg  = (__hip_bfloat16*)(ws + off); off += (size_t)kB * kH * 2;
  __hip_bfloat16* xb  = (__hip_bfloat16*)(ws + off); off += (size_t)kB * kS * kI * 2;
  __hip_bfloat16* WtIn   = (__hip_bfloat16*)(ws + off); off += (size_t)kH * (kH + kI) * 2;
  __hip_bfloat16* WtPass = (__hip_bfloat16*)(ws + off); off += (size_t)kH * kH * 2;
  __hip_bfloat16* WtTau  = (__hip_bfloat16*)(ws + off); off += (size_t)kH * kH * 2;
  __hip_bfloat16* WtMem  = (__hip_bfloat16*)(ws + off); off += (size_t)kH * kH * 2;
  __hip_bfloat16* WtOut  = (__hip_bfloat16*)(ws + off); off += (size_t)kC * kH * 2;

  // zero barrier flags + initial h0 (buffer starts at zero)
  hipMemsetAsync(d_ws, 0, 8448 + (size_t)kB * kH * 2, stream);

  prep<<<1024, 256, 0, stream>>>(x, W_in, W_pass, W_tau, W_mem, W_out,
                                 xb, WtIn, WtPass, WtTau, WtMem, WtOut);

  KParams P;
  P.xb = xb; P.WtIn = WtIn; P.WtPass = WtPass; P.WtTau = WtTau; P.WtMem = WtMem;
  P.WtOut = WtOut; P.h0g = h0g; P.hpg = hpg; P.hg = hg;
  P.arrive = arrive; P.release = release; P.lengths = lens;
  P.b_in = b_in; P.b_pass = b_pass; P.b_tau = b_tau; P.b_mem = b_mem; P.b_out = b_out;
  P.dout = (float*)d_out;

  // grid (32) << CU count (256): all blocks co-resident, spin barrier is safe.
  rnn_main<<<dim3(kNWG), dim3(256), 0, stream>>>(P);
}

// Round 2
// 5275.421 us; speedup vs baseline: 1.3034x; 1.3034x over previous
//
#include <hip/hip_runtime.h>
#include <hip/hip_bf16.h>

// DelayRNN on MI355X — Round 2.
// 32 persistent WGs, each owns 16 hidden cols. Per step, everything is linear
// in z=[h0,x_t]: 6 composite GEMM outputs (h_pre, p, tauA, tauB, memA, memB),
// K=640, computed with MFMA from bf16 composite weights (precomputed on device).
// Binary mask => exact select between A/B paths. ONE grid barrier per step.
// All cross-WG traffic (h0 slices + flags) via agent-scope relaxed atomics
// (coherence-point accesses) — NO fences => per-XCD L2 never invalidated =>
// weights stay cache-resident. h0 ping-pong double buffered.

constexpr int kB    = 32;
constexpr int kS    = 256;
constexpr int kI    = 128;
constexpr int kH    = 512;
constexpr int kC    = 64;
constexpr int kOutL = 64;
constexpr int kMaxD = 16;
constexpr int kBufD = 17;
constexpr int kNWG  = 32;
constexpr int kJPW  = 16;
constexpr int kSteps = kS + kOutL;   // 320
constexpr int kKz   = kH + kI;       // 640 (uniform K for all 6 composites)

typedef __bf16 bf16x8 __attribute__((ext_vector_type(8)));
typedef float  f32x4  __attribute__((ext_vector_type(4)));

__device__ __forceinline__ f32x4 MFMA(bf16x8 a, bf16x8 b, f32x4 c) {
  return __builtin_amdgcn_mfma_f32_16x16x32_bf16(a, b, c, 0, 0, 0);
}
__device__ __forceinline__ bf16x8 ld8(const __hip_bfloat16* p) {
  return *reinterpret_cast<const bf16x8*>(p);
}
// Coherent (coherence-point) 16B load as 2x8B agent-scope relaxed atomics.
__device__ __forceinline__ bf16x8 ld8_atomic(const __hip_bfloat16* p) {
  unsigned long long u0 = __hip_atomic_load((unsigned long long*)p,
      __ATOMIC_RELAXED, __HIP_MEMORY_SCOPE_AGENT);
  unsigned long long u1 = __hip_atomic_load((unsigned long long*)p + 1,
      __ATOMIC_RELAXED, __HIP_MEMORY_SCOPE_AGENT);
  union { unsigned long long u[2]; bf16x8 v; } c;
  c.u[0] = u0; c.u[1] = u1;
  return c.v;
}
__device__ __forceinline__ bf16x8 ld8_f32(const float* p) {
  float4 a = *(const float4*)p, b = *(const float4*)(p + 4);
  union { __hip_bfloat16 h[8]; bf16x8 v; } c;
  c.h[0] = __float2bfloat16(a.x); c.h[1] = __float2bfloat16(a.y);
  c.h[2] = __float2bfloat16(a.z); c.h[3] = __float2bfloat16(a.w);
  c.h[4] = __float2bfloat16(b.x); c.h[5] = __float2bfloat16(b.y);
  c.h[6] = __float2bfloat16(b.z); c.h[7] = __float2bfloat16(b.w);
  return c.v;
}
__device__ __forceinline__ bf16x8 zero8() {
  union { unsigned long long u[2]; bf16x8 v; } c;
  c.u[0] = 0ull; c.u[1] = 0ull;
  return c.v;
}
__device__ __forceinline__ float sigm(float x) { return 1.0f / (1.0f + __expf(-x)); }

// ---------------- prep kernels ----------------

// Transpose-cast W_in -> Wall[0] ([col][k], k over 640), W_pass/tau/mem ->
// Bt ([col][k]) for composite matmuls, W_out -> WtOut ([c][k]).
__global__ void prep_cast(const float* W_in, const float* W_pass, const float* W_tau,
                          const float* W_mem, const float* W_out,
                          __hip_bfloat16* Wall, __hip_bfloat16* BtP, __hip_bfloat16* BtT,
                          __hip_bfloat16* BtM, __hip_bfloat16* WtOut) {
  const int tid = blockIdx.x * blockDim.x + threadIdx.x;
  const int nth = gridDim.x * blockDim.x;
  for (int i = tid; i < kH * kKz; i += nth) {
    int j = i / kKz, k = i - j * kKz;
    Wall[i] = __float2bfloat16(W_in[k * kH + j]);
  }
  for (int i = tid; i < kH * kH; i += nth) {
    int j = i >> 9, k = i & 511;
    BtP[i] = __float2bfloat16(W_pass[k * kH + j]);
    BtT[i] = __float2bfloat16(W_tau[k * kH + j]);
    BtM[i] = __float2bfloat16(W_mem[k * kH + j]);
  }
  for (int i = tid; i < kC * kH; i += nth) {
    int c = i >> 9, k = i & 511;
    WtOut[i] = __float2bfloat16(W_out[k * kC + c]);
  }
}

// Composite biases: [6][512] = {b_in, b_in@Wp+b_p, b_in@Wt+b_t, biasP@Wt+b_t,
//                               b_in@Wm+b_m, biasP@Wm+b_m}
__global__ void prep_bias(const float* b_in, const float* b_pass, const float* b_tau,
                          const float* b_mem, const float* W_pass, const float* W_tau,
                          const float* W_mem, float* bias) {
  __shared__ float bp_s[kH];
  const int j = threadIdx.x;
  float s1 = 0.f, s2 = 0.f, s3 = 0.f;
  for (int k = 0; k < kH; ++k) {
    float bi = b_in[k];
    s1 += bi * W_pass[k * kH + j];
    s2 += bi * W_tau[k * kH + j];
    s3 += bi * W_mem[k * kH + j];
  }
  float bP = s1 + b_pass[j];
  bias[j]          = b_in[j];
  bias[kH + j]     = bP;
  bias[2 * kH + j] = s2 + b_tau[j];
  bias[4 * kH + j] = s3 + b_mem[j];
  bp_s[j] = bP;
  __syncthreads();
  float s4 = 0.f, s5 = 0.f;
  for (int k = 0; k < kH; ++k) {
    float v = bp_s[k];
    s4 += v * W_tau[k * kH + j];
    s5 += v * W_mem[k * kH + j];
  }
  bias[3 * kH + j] = s4 + b_tau[j];
  bias[5 * kH + j] = s5 + b_mem[j];
}

// Stage-1 composites: W_in @ {W_pass, W_tau, W_mem} -> Wall[1],[2],[4]
// (stored transposed [col][k]); the W_pass product also kept row-major bf16 (Cip).
__global__ __launch_bounds__(64) void prep_mm1(const float* W_in, const __hip_bfloat16* BtP,
    const __hip_bfloat16* BtT, const __hip_bfloat16* BtM,
    __hip_bfloat16* Wall, __hip_bfloat16* Cip) {
  const int bm = blockIdx.x, bn = blockIdx.y, z = blockIdx.z;
  const int lane = threadIdx.x;
  const int kq = (lane >> 4) * 8;
  const __hip_bfloat16* Bt = (z == 0) ? BtP : (z == 1 ? BtT : BtM);
  const int mat = (z == 0) ? 1 : (z == 1 ? 2 : 4);
  const float* arow = W_in + (size_t)(bm * 16 + (lane & 15)) * kH;
  const __hip_bfloat16* brow = Bt + (size_t)(bn * 16 + (lane & 15)) * kH;
  f32x4 acc = {0.f, 0.f, 0.f, 0.f};
  for (int i = 0; i < 16; ++i) {
    const int kk = i * 32 + kq;
    acc = MFMA(ld8_f32(arow + kk), ld8(brow + kk), acc);
  }
  const int rm = (lane >> 4) * 4, cn = lane & 15;
  union { __hip_bfloat16 h[4]; ushort4 s; } cv;
#pragma unroll
  for (int r = 0; r < 4; ++r) cv.h[r] = __float2bfloat16(acc[r]);
  __hip_bfloat16* wd = Wall + ((size_t)mat * kH + bn * 16 + cn) * kKz + bm * 16 + rm;
  *(ushort4*)wd = cv.s;
  if (z == 0) {
#pragma unroll
    for (int r = 0; r < 4; ++r)
      Cip[(size_t)(bm * 16 + rm + r) * kH + bn * 16 + cn] = cv.h[r];
  }
}

// Stage-2 composites: Cip @ {W_tau, W_mem} -> Wall[3],[5]
__global__ __launch_bounds__(64) void prep_mm2(const __hip_bfloat16* Cip,
    const __hip_bfloat16* BtT, const __hip_bfloat16* BtM, __hip_bfloat16* Wall) {
  const int bm = blockIdx.x, bn = blockIdx.y, z = blockIdx.z;
  const int lane = threadIdx.x;
  const int kq = (lane >> 4) * 8;
  const __hip_bfloat16* Bt = (z == 0) ? BtT : BtM;
  const int mat = (z == 0) ? 3 : 5;
  const __hip_bfloat16* arow = Cip + (size_t)(bm * 16 + (lane & 15)) * kH;
  const __hip_bfloat16* brow = Bt + (size_t)(bn * 16 + (lane & 15)) * kH;
  f32x4 acc = {0.f, 0.f, 0.f, 0.f};
  for (int i = 0; i < 16; ++i) {
    const int kk = i * 32 + kq;
    acc = MFMA(ld8(arow + kk), ld8(brow + kk), acc);
  }
  const int rm = (lane >> 4) * 4, cn = lane & 15;
  union { __hip_bfloat16 h[4]; ushort4 s; } cv;
#pragma unroll
  for (int r = 0; r < 4; ++r) cv.h[r] = __float2bfloat16(acc[r]);
  __hip_bfloat16* wd = Wall + ((size_t)mat * kH + bn * 16 + cn) * kKz + bm * 16 + rm;
  *(ushort4*)wd = cv.s;
}

// ---------------- main persistent kernel ----------------

struct KParams {
  const float* x;                 // fp32 input [B][S][I]
  const __hip_bfloat16* Wall;     // [6][512][640] composites, [col][k]
  const __hip_bfloat16* WtOut;    // [64][512]
  const float* bias;              // [6][512]
  const float* b_out;             // [64]
  __hip_bfloat16* h0a;            // ping
  __hip_bfloat16* h0b;            // pong
  int* arrive;                    // [32] flags (stride 16 ints)
  const int* lengths;
  float* dout;                    // [B][kOutL][C]
};

__global__ __launch_bounds__(256) void rnn_main(KParams P) {
  __shared__ float buf[kB][kJPW][kBufD];      // delay buffer (owner-exclusive)
  __shared__ float outLDS[6][kB][kJPW + 1];   // 6 GEMM outputs for owned cols
  __shared__ int   len_s[kB];

  const int wg = blockIdx.x, tid = threadIdx.x;
  const int lane = tid & 63, wave = tid >> 6;
  const int mt = wave & 1;        // batch half
  const int ng = wave >> 1;       // matrix triple {0,1,2} or {3,4,5}
  const int rowA = mt * 16 + (lane & 15);
  const int kq = (lane >> 4) * 8;
  const int jn = wg * kJPW + (lane & 15);
  const __hip_bfloat16* Wb0 = P.Wall + ((size_t)(ng * 3) * kH + jn) * kKz;
  const __hip_bfloat16* Wb1 = Wb0 + (size_t)kH * kKz;
  const __hip_bfloat16* Wb2 = Wb1 + (size_t)kH * kKz;
  const int eb = tid >> 3, eq = tid & 7;      // epilogue: (batch, col-pair)

  for (int i = tid; i < kB * kJPW * kBufD; i += 256) (&buf[0][0][0])[i] = 0.f;
  if (tid < kB) len_s[tid] = P.lengths[tid];
  __syncthreads();

  for (int t = 0; t < kSteps; ++t) {
    const __hip_bfloat16* h0r = (t & 1) ? P.h0b : P.h0a;
    __hip_bfloat16*       h0w = (t & 1) ? P.h0a : P.h0b;

    // ---- decode output GEMV: out = h0 @ W_out + b_out (pre-update h0) ----
    if (t >= kS) {
      const int cl = tid >> 7, b = (tid >> 2) & 31, qq = tid & 3;
      const int c = wg * 2 + cl;
      const __hip_bfloat16* hrow = h0r + b * kH;
      const __hip_bfloat16* wrow = P.WtOut + c * kH;
      float s = 0.f;
      for (int j = qq * 128; j < qq * 128 + 128; j += 8) {
        union { unsigned long long u[2]; __hip_bfloat16 h[8]; } hu, wu;
        hu.u[0] = __hip_atomic_load((unsigned long long*)(hrow + j),
                                    __ATOMIC_RELAXED, __HIP_MEMORY_SCOPE_AGENT);
        hu.u[1] = __hip_atomic_load((unsigned long long*)(hrow + j) + 1,
                                    __ATOMIC_RELAXED, __HIP_MEMORY_SCOPE_AGENT);
        wu.u[0] = *(const unsigned long long*)(wrow + j);
        wu.u[1] = *((const unsigned long long*)(wrow + j) + 1);
#pragma unroll
        for (int u = 0; u < 8; ++u)
          s += __bfloat162float(hu.h[u]) * __bfloat162float(wu.h[u]);
      }
      s += __shfl_xor(s, 1);
      s += __shfl_xor(s, 2);
      if (qq == 0) P.dout[b * (kOutL * kC) + (t - kS) * kC + c] = s + P.b_out[c];
    }

    // ---- 6-way composite GEMM: z=[h0,x_t] (K=640) -> owned 16 cols ----
    {
      f32x4 a0 = {0.f,0.f,0.f,0.f}, a1 = {0.f,0.f,0.f,0.f}, a2 = {0.f,0.f,0.f,0.f};
      const __hip_bfloat16* hrow = h0r + rowA * kH;
#pragma unroll 4
      for (int i = 0; i < 16; ++i) {
        const int kk = i * 32 + kq;
        bf16x8 av = ld8_atomic(hrow + kk);       // coherent read of shared h0
        a0 = MFMA(av, ld8(Wb0 + kk), a0);
        a1 = MFMA(av, ld8(Wb1 + kk), a1);
        a2 = MFMA(av, ld8(Wb2 + kk), a2);
      }
      const float* xrow = P.x + ((size_t)rowA * kS + t) * kI;
#pragma unroll
      for (int i = 16; i < 20; ++i) {
        const int kk = i * 32 + kq;
        bf16x8 av = (t < kS) ? ld8_f32(xrow + (kk - kH)) : zero8();
        a0 = MFMA(av, ld8(Wb0 + kk), a0);
        a1 = MFMA(av, ld8(Wb1 + kk), a1);
        a2 = MFMA(av, ld8(Wb2 + kk), a2);
      }
#pragma unroll
      for (int r = 0; r < 4; ++r) {
        const int br = mt * 16 + (lane >> 4) * 4 + r, cn = lane & 15;
        outLDS[ng * 3 + 0][br][cn] = a0[r];
        outLDS[ng * 3 + 1][br][cn] = a1[r];
        outLDS[ng * 3 + 2][br][cn] = a2[r];
      }
    }
    __syncthreads();

    // ---- epilogue: blend by mask, gates, delay-buffer update, new h0 ----
    {
      unsigned int pk = 0;
#pragma unroll
      for (int u = 0; u < 2; ++u) {
        const int jl = eq * 2 + u, j = wg * kJPW + jl;
        float hp = outLDS[0][eb][jl] + P.bias[j];
        float pv = outLDS[1][eb][jl] + P.bias[kH + j];
        float ta = outLDS[2][eb][jl] + P.bias[2 * kH + j];
        float tb = outLDS[3][eb][jl] + P.bias[3 * kH + j];
        float ma = outLDS[4][eb][jl] + P.bias[4 * kH + j];
        float mb = outLDS[5][eb][jl] + P.bias[5 * kH + j];
        const bool msk = (t >= kS) || (t < len_s[eb]);   // binary mask: exact select
        float hv = msk ? pv : hp;
        float gt = msk ? tb : ta;
        float gm = msk ? mb : ma;
        float tau = 16.f * sigm(gt);
        tau = fminf(fmaxf(tau, 1.f), 16.f);
        float ml = sigm(gm);
        float* bp = buf[eb][jl];
        float front = 0.f;
#pragma unroll
        for (int d = 1; d <= kMaxD; ++d) {
          float w = ml / (1.f + fabsf(tau - (float)d));
          float nv = bp[d] + w * hv;
          bp[d - 1] = nv;
          if (d == 1) front = nv;
        }
        bp[kMaxD] = 0.f;
        __hip_bfloat16 hb = __float2bfloat16(front);
        unsigned short bits = *(unsigned short*)&hb;
        pk |= ((unsigned int)bits) << (16 * u);
      }
      // publish owned h0 pair via coherence-point store
      __hip_atomic_store((unsigned int*)(h0w + eb * kH + wg * kJPW + eq * 2), pk,
                         __ATOMIC_RELAXED, __HIP_MEMORY_SCOPE_AGENT);
    }

    // ---- fence-free leaderless grid barrier (1 coherence hop) ----
    __builtin_amdgcn_s_waitcnt(0);      // all atomic stores at coherence point
    __syncthreads();                    // every wave's stores drained
    if (tid == 0)
      __hip_atomic_store(&P.arrive[wg * 16], t + 1,
                         __ATOMIC_RELAXED, __HIP_MEMORY_SCOPE_AGENT);
    if (tid < kNWG) {
      while (__hip_atomic_load(&P.arrive[tid * 16],
                               __ATOMIC_RELAXED, __HIP_MEMORY_SCOPE_AGENT) < t + 1)
        __builtin_amdgcn_s_sleep(1);
    }
    __syncthreads();
    asm volatile("" ::: "memory");      // keep next step's loads after the spin
  }
}

extern "C" void kernel_launch(void* const* d_in, const int* in_sizes, int n_in,
                              void* d_out, int out_size, void* d_ws, size_t ws_size,
                              hipStream_t stream) {
  const float* x      = (const float*)d_in[0];
  const int*   lens   = (const int*)d_in[1];
  const float* W_in   = (const float*)d_in[3];
  const float* b_in   = (const float*)d_in[4];
  const float* W_pass = (const float*)d_in[5];
  const float* b_pass = (const float*)d_in[6];
  const float* W_tau  = (const float*)d_in[7];
  const float* b_tau  = (const float*)d_in[8];
  const float* W_mem  = (const float*)d_in[9];
  const float* b_mem  = (const float*)d_in[10];
  const float* W_out  = (const float*)d_in[11];
  const float* b_out  = (const float*)d_in[12];

  char* ws = (char*)d_ws;
  size_t off = 0;
  int* arrive = (int*)(ws + off);                 off += 2048;                        // 32 flags, 64B stride
  __hip_bfloat16* h0a = (__hip_bfloat16*)(ws + off); off += (size_t)kB * kH * 2;      // 32KB
  __hip_bfloat16* h0b = (__hip_bfloat16*)(ws + off); off += (size_t)kB * kH * 2;      // 32KB
  float* bias = (float*)(ws + off);               off += 6 * kH * sizeof(float);      // 12KB
  __hip_bfloat16* WtOut = (__hip_bfloat16*)(ws + off); off += (size_t)kC * kH * 2;    // 64KB
  __hip_bfloat16* Wall  = (__hip_bfloat16*)(ws + off); off += (size_t)6 * kH * kKz * 2; // 3.93MB
  __hip_bfloat16* BtP   = (__hip_bfloat16*)(ws + off); off += (size_t)kH * kH * 2;
  __hip_bfloat16* BtT   = (__hip_bfloat16*)(ws + off); off += (size_t)kH * kH * 2;
  __hip_bfloat16* BtM   = (__hip_bfloat16*)(ws + off); off += (size_t)kH * kH * 2;
  __hip_bfloat16* Cip   = (__hip_bfloat16*)(ws + off); off += (size_t)kKz * kH * 2;   // ~6.3MB total

  // zero flags + initial h0 ping buffer (d_ws is poisoned 0xAA each launch)
  hipMemsetAsync(d_ws, 0, 2048 + 2 * (size_t)kB * kH * 2, stream);

  prep_cast<<<512, 256, 0, stream>>>(W_in, W_pass, W_tau, W_mem, W_out,
                                     Wall, BtP, BtT, BtM, WtOut);
  prep_bias<<<1, 512, 0, stream>>>(b_in, b_pass, b_tau, b_mem, W_pass, W_tau, W_mem, bias);
  prep_mm1<<<dim3(40, 32, 3), 64, 0, stream>>>(W_in, BtP, BtT, BtM, Wall, Cip);
  prep_mm2<<<dim3(40, 32, 2), 64, 0, stream>>>(Cip, BtT, BtM, Wall);

  KParams P;
  P.x = x; P.Wall = Wall; P.WtOut = WtOut; P.bias = bias; P.b_out = b_out;
  P.h0a = h0a; P.h0b = h0b; P.arrive = arrive; P.lengths = lens;
  P.dout = (float*)d_out;

  rnn_main<<<dim3(kNWG), dim3(256), 0, stream>>>(P);
}

// Round 4
// 3478.754 us; speedup vs baseline: 1.9766x; 1.5165x over previous
//
#include <hip/hip_runtime.h>
#include <hip/hip_bf16.h>

// DelayRNN on MI355X — Round 4 (= R3 design + fixed x-staging indexing).
// Column-partitioned persistent kernel (32 WGs × 16 hidden cols), composite
// weights => ONE grid barrier per step. h0 staged into LDS once per WG via
// batched 16B coherent loads (global_load_dwordx4 sc0 sc1 — cache-bypass,
// non-atomic, fully pipelined). GEMM A-frags + decode GEMV read LDS.
// Delay buffer in registers (1 WG/CU, occupancy irrelevant).

constexpr int kB    = 32;
constexpr int kS    = 256;
constexpr int kI    = 128;
constexpr int kH    = 512;
constexpr int kC    = 64;
constexpr int kOutL = 64;
constexpr int kMaxD = 16;
constexpr int kBufD = 17;
constexpr int kNWG  = 32;
constexpr int kJPW  = 16;
constexpr int kSteps = kS + kOutL;   // 320
constexpr int kKz   = kH + kI;       // 640
constexpr int kZPad = 8;             // z row pad -> stride 648 elem (1296B)

typedef __bf16 bf16x8 __attribute__((ext_vector_type(8)));
typedef float  f32x4  __attribute__((ext_vector_type(4)));
typedef unsigned int u32x4 __attribute__((ext_vector_type(4)));

__device__ __forceinline__ f32x4 MFMA(bf16x8 a, bf16x8 b, f32x4 c) {
  return __builtin_amdgcn_mfma_f32_16x16x32_bf16(a, b, c, 0, 0, 0);
}
__device__ __forceinline__ bf16x8 ld8(const __hip_bfloat16* p) {
  return *reinterpret_cast<const bf16x8*>(p);
}
__device__ __forceinline__ bf16x8 ld8_f32(const float* p) {
  float4 a = *(const float4*)p, b = *(const float4*)(p + 4);
  union { __hip_bfloat16 h[8]; bf16x8 v; } c;
  c.h[0] = __float2bfloat16(a.x); c.h[1] = __float2bfloat16(a.y);
  c.h[2] = __float2bfloat16(a.z); c.h[3] = __float2bfloat16(a.w);
  c.h[4] = __float2bfloat16(b.x); c.h[5] = __float2bfloat16(b.y);
  c.h[6] = __float2bfloat16(b.z); c.h[7] = __float2bfloat16(b.w);
  return c.v;
}
__device__ __forceinline__ float sigm(float x) { return 1.0f / (1.0f + __expf(-x)); }

// ---------------- prep kernels ----------------

__global__ void prep_cast(const float* x, const float* W_in, const float* W_pass,
                          const float* W_tau, const float* W_mem, const float* W_out,
                          __hip_bfloat16* xb, __hip_bfloat16* Wall, __hip_bfloat16* BtP,
                          __hip_bfloat16* BtT, __hip_bfloat16* BtM, __hip_bfloat16* WtOut) {
  const int tid = blockIdx.x * blockDim.x + threadIdx.x;
  const int nth = gridDim.x * blockDim.x;
  for (int i = tid; i < kB * kS * kI; i += nth) xb[i] = __float2bfloat16(x[i]);
  for (int i = tid; i < kH * kKz; i += nth) {
    int j = i / kKz, k = i - j * kKz;
    Wall[i] = __float2bfloat16(W_in[k * kH + j]);
  }
  for (int i = tid; i < kH * kH; i += nth) {
    int j = i >> 9, k = i & 511;
    BtP[i] = __float2bfloat16(W_pass[k * kH + j]);
    BtT[i] = __float2bfloat16(W_tau[k * kH + j]);
    BtM[i] = __float2bfloat16(W_mem[k * kH + j]);
  }
  for (int i = tid; i < kC * kH; i += nth) {
    int c = i >> 9, k = i & 511;
    WtOut[i] = __float2bfloat16(W_out[k * kC + c]);
  }
}

__global__ void prep_bias(const float* b_in, const float* b_pass, const float* b_tau,
                          const float* b_mem, const float* W_pass, const float* W_tau,
                          const float* W_mem, float* bias) {
  __shared__ float bp_s[kH];
  const int j = threadIdx.x;
  float s1 = 0.f, s2 = 0.f, s3 = 0.f;
  for (int k = 0; k < kH; ++k) {
    float bi = b_in[k];
    s1 += bi * W_pass[k * kH + j];
    s2 += bi * W_tau[k * kH + j];
    s3 += bi * W_mem[k * kH + j];
  }
  float bP = s1 + b_pass[j];
  bias[j]          = b_in[j];
  bias[kH + j]     = bP;
  bias[2 * kH + j] = s2 + b_tau[j];
  bias[4 * kH + j] = s3 + b_mem[j];
  bp_s[j] = bP;
  __syncthreads();
  float s4 = 0.f, s5 = 0.f;
  for (int k = 0; k < kH; ++k) {
    float v = bp_s[k];
    s4 += v * W_tau[k * kH + j];
    s5 += v * W_mem[k * kH + j];
  }
  bias[3 * kH + j] = s4 + b_tau[j];
  bias[5 * kH + j] = s5 + b_mem[j];
}

__global__ __launch_bounds__(64) void prep_mm1(const float* W_in, const __hip_bfloat16* BtP,
    const __hip_bfloat16* BtT, const __hip_bfloat16* BtM,
    __hip_bfloat16* Wall, __hip_bfloat16* Cip) {
  const int bm = blockIdx.x, bn = blockIdx.y, z = blockIdx.z;
  const int lane = threadIdx.x;
  const int kq = (lane >> 4) * 8;
  const __hip_bfloat16* Bt = (z == 0) ? BtP : (z == 1 ? BtT : BtM);
  const int mat = (z == 0) ? 1 : (z == 1 ? 2 : 4);
  const float* arow = W_in + (size_t)(bm * 16 + (lane & 15)) * kH;
  const __hip_bfloat16* brow = Bt + (size_t)(bn * 16 + (lane & 15)) * kH;
  f32x4 acc = {0.f, 0.f, 0.f, 0.f};
  for (int i = 0; i < 16; ++i) {
    const int kk = i * 32 + kq;
    acc = MFMA(ld8_f32(arow + kk), ld8(brow + kk), acc);
  }
  const int rm = (lane >> 4) * 4, cn = lane & 15;
  union { __hip_bfloat16 h[4]; ushort4 s; } cv;
#pragma unroll
  for (int r = 0; r < 4; ++r) cv.h[r] = __float2bfloat16(acc[r]);
  __hip_bfloat16* wd = Wall + ((size_t)mat * kH + bn * 16 + cn) * kKz + bm * 16 + rm;
  *(ushort4*)wd = cv.s;
  if (z == 0) {
#pragma unroll
    for (int r = 0; r < 4; ++r)
      Cip[(size_t)(bm * 16 + rm + r) * kH + bn * 16 + cn] = cv.h[r];
  }
}

__global__ __launch_bounds__(64) void prep_mm2(const __hip_bfloat16* Cip,
    const __hip_bfloat16* BtT, const __hip_bfloat16* BtM, __hip_bfloat16* Wall) {
  const int bm = blockIdx.x, bn = blockIdx.y, z = blockIdx.z;
  const int lane = threadIdx.x;
  const int kq = (lane >> 4) * 8;
  const __hip_bfloat16* Bt = (z == 0) ? BtT : BtM;
  const int mat = (z == 0) ? 3 : 5;
  const __hip_bfloat16* arow = Cip + (size_t)(bm * 16 + (lane & 15)) * kH;
  const __hip_bfloat16* brow = Bt + (size_t)(bn * 16 + (lane & 15)) * kH;
  f32x4 acc = {0.f, 0.f, 0.f, 0.f};
  for (int i = 0; i < 16; ++i) {
    const int kk = i * 32 + kq;
    acc = MFMA(ld8(arow + kk), ld8(brow + kk), acc);
  }
  const int rm = (lane >> 4) * 4, cn = lane & 15;
  union { __hip_bfloat16 h[4]; ushort4 s; } cv;
#pragma unroll
  for (int r = 0; r < 4; ++r) cv.h[r] = __float2bfloat16(acc[r]);
  __hip_bfloat16* wd = Wall + ((size_t)mat * kH + bn * 16 + cn) * kKz + bm * 16 + rm;
  *(ushort4*)wd = cv.s;
}

// ---------------- main persistent kernel ----------------

struct KParams {
  const __hip_bfloat16* xb;       // bf16 input [B][S][I]
  const __hip_bfloat16* Wall;     // [6][512][640] composites, [col][k]
  const __hip_bfloat16* WtOut;    // [64][512]
  const float* bias;              // [6][512]
  const float* b_out;             // [64]
  __hip_bfloat16* h0a;            // ping
  __hip_bfloat16* h0b;            // pong
  int* arrive;                    // [32] flags, 64B stride
  const int* lengths;
  float* dout;                    // [B][kOutL][C]
};

__global__ __launch_bounds__(256, 1) void rnn_main(KParams P) {
  // z = [h0 (512) | x_t (128) | pad 8] per batch row, bf16. 41,472 B
  __shared__ __align__(16) __hip_bfloat16 zs[kB][kKz + kZPad];
  __shared__ float outLDS[6][kB][kJPW + 1];   // 13,056 B
  __shared__ int   len_s[kB];

  const int wg = blockIdx.x, tid = threadIdx.x;
  const int lane = tid & 63, wave = tid >> 6;
  const int mt = wave & 1;        // batch half
  const int ng = wave >> 1;       // matrix triple {0,1,2} / {3,4,5}
  const int rowA = mt * 16 + (lane & 15);
  const int kq = (lane >> 4) * 8;
  const int jn = wg * kJPW + (lane & 15);
  const __hip_bfloat16* Wb0 = P.Wall + ((size_t)(ng * 3) * kH + jn) * kKz;
  const __hip_bfloat16* Wb1 = Wb0 + (size_t)kH * kKz;
  const __hip_bfloat16* Wb2 = Wb1 + (size_t)kH * kKz;
  const int eb = tid >> 3, eq = tid & 7;      // epilogue: batch, col-pair

  // Delay buffer in registers: thread owns cols {eq*2, eq*2+1} of batch eb.
  float bufr[2][kBufD];
#pragma unroll
  for (int u = 0; u < 2; ++u)
#pragma unroll
    for (int d = 0; d < kBufD; ++d) bufr[u][d] = 0.f;

  if (tid < kB) len_s[tid] = P.lengths[tid];
  __syncthreads();

  // h0 staging: 32KB = 2048 x 16B chunks; thread covers 8 (one per 4-row band).
  const unsigned vo = tid * 16u;
  const int r0 = tid >> 6;          // row base (0..3), rows advance by 4/chunk
  const int cin = tid & 63;         // 16B chunk within row

  // x staging: row tid>>3 (0..31), chunks {tid&7, 8+(tid&7)} of 16 per row.
  const int xrow = tid >> 3;
  const int xch  = tid & 7;

  for (int t = 0; t < kSteps; ++t) {
    const __hip_bfloat16* h0r = (t & 1) ? P.h0b : P.h0a;
    __hip_bfloat16*       h0w = (t & 1) ? P.h0a : P.h0b;

    // ---- stage h0 -> LDS via coherent 16B loads (cache-bypass, one drain) ----
    {
      u32x4 q0, q1, q2, q3, q4, q5, q6, q7;
      asm volatile(
          "global_load_dwordx4 %0, %8, %16 sc0 sc1\n\t"
          "global_load_dwordx4 %1, %9, %16 sc0 sc1\n\t"
          "global_load_dwordx4 %2, %10, %16 sc0 sc1\n\t"
          "global_load_dwordx4 %3, %11, %16 sc0 sc1\n\t"
          "global_load_dwordx4 %4, %12, %16 sc0 sc1\n\t"
          "global_load_dwordx4 %5, %13, %16 sc0 sc1\n\t"
          "global_load_dwordx4 %6, %14, %16 sc0 sc1\n\t"
          "global_load_dwordx4 %7, %15, %16 sc0 sc1\n\t"
          "s_waitcnt vmcnt(0)"
          : "=&v"(q0), "=&v"(q1), "=&v"(q2), "=&v"(q3),
            "=&v"(q4), "=&v"(q5), "=&v"(q6), "=&v"(q7)
          : "v"(vo), "v"(vo + 4096u), "v"(vo + 8192u), "v"(vo + 12288u),
            "v"(vo + 16384u), "v"(vo + 20480u), "v"(vo + 24576u), "v"(vo + 28672u),
            "s"(h0r)
          : "memory");
      *(u32x4*)&zs[r0 +  0][cin * 8] = q0;
      *(u32x4*)&zs[r0 +  4][cin * 8] = q1;
      *(u32x4*)&zs[r0 +  8][cin * 8] = q2;
      *(u32x4*)&zs[r0 + 12][cin * 8] = q3;
      *(u32x4*)&zs[r0 + 16][cin * 8] = q4;
      *(u32x4*)&zs[r0 + 20][cin * 8] = q5;
      *(u32x4*)&zs[r0 + 24][cin * 8] = q6;
      *(u32x4*)&zs[r0 + 28][cin * 8] = q7;
    }

    // ---- stage x_t (bf16, cached): 16 chunks/row, 2 per thread ----
    if (t < kS) {
#pragma unroll
      for (int i = 0; i < 2; ++i) {
        const int c2 = i * 8 + xch;       // chunk 0..15 within row's x region
        const u32x4 xv = *(const u32x4*)(P.xb + ((size_t)xrow * kS + t) * kI + c2 * 8);
        *(u32x4*)&zs[xrow][kH + c2 * 8] = xv;
      }
    } else if (t == kS) {
      const u32x4 zv = {0u, 0u, 0u, 0u};
#pragma unroll
      for (int i = 0; i < 2; ++i) {
        const int c2 = i * 8 + xch;
        *(u32x4*)&zs[xrow][kH + c2 * 8] = zv;
      }
    }
    __syncthreads();

    // ---- decode output GEMV from LDS: out = h0 @ W_out + b_out ----
    if (t >= kS) {
      const int cl = tid >> 7, b = (tid >> 2) & 31, qq = tid & 3;
      const int c = wg * 2 + cl;
      const __hip_bfloat16* wrow = P.WtOut + c * kH;
      float s = 0.f;
#pragma unroll
      for (int jj = 0; jj < 16; ++jj) {
        const int j = qq * 8 + jj * 32;   // interleave across LDS banks
        bf16x8 hv = *(const bf16x8*)&zs[b][j];
        bf16x8 wv = ld8(wrow + j);
#pragma unroll
        for (int u = 0; u < 8; ++u)
          s += (float)hv[u] * (float)wv[u];
      }
      s += __shfl_xor(s, 1);
      s += __shfl_xor(s, 2);
      if (qq == 0) P.dout[b * (kOutL * kC) + (t - kS) * kC + c] = s + P.b_out[c];
    }

    // ---- 6-way composite GEMM: z (K=640) -> owned 16 cols; A from LDS ----
    {
      f32x4 a0 = {0.f,0.f,0.f,0.f}, a1 = {0.f,0.f,0.f,0.f}, a2 = {0.f,0.f,0.f,0.f};
#pragma unroll
      for (int i = 0; i < 20; ++i) {
        const int kk = i * 32 + kq;
        bf16x8 av = *(const bf16x8*)&zs[rowA][kk];
        a0 = MFMA(av, ld8(Wb0 + kk), a0);
        a1 = MFMA(av, ld8(Wb1 + kk), a1);
        a2 = MFMA(av, ld8(Wb2 + kk), a2);
      }
#pragma unroll
      for (int r = 0; r < 4; ++r) {
        const int br = mt * 16 + (lane >> 4) * 4 + r, cn = lane & 15;
        outLDS[ng * 3 + 0][br][cn] = a0[r];
        outLDS[ng * 3 + 1][br][cn] = a1[r];
        outLDS[ng * 3 + 2][br][cn] = a2[r];
      }
    }
    __syncthreads();

    // ---- epilogue: blend, gates, register delay-buffer update, publish h0 ----
    {
      unsigned int pk = 0;
      const bool msk = (t >= kS) || (t < len_s[eb]);
#pragma unroll
      for (int u = 0; u < 2; ++u) {
        const int jl = eq * 2 + u, j = wg * kJPW + jl;
        float hp = outLDS[0][eb][jl] + P.bias[j];
        float pv = outLDS[1][eb][jl] + P.bias[kH + j];
        float ta = outLDS[2][eb][jl] + P.bias[2 * kH + j];
        float tb = outLDS[3][eb][jl] + P.bias[3 * kH + j];
        float ma = outLDS[4][eb][jl] + P.bias[4 * kH + j];
        float mb = outLDS[5][eb][jl] + P.bias[5 * kH + j];
        float hv = msk ? pv : hp;
        float gt = msk ? tb : ta;
        float gm = msk ? mb : ma;
        float tau = 16.f * sigm(gt);
        tau = fminf(fmaxf(tau, 1.f), 16.f);
        float ml = sigm(gm);
        float front = 0.f;
#pragma unroll
        for (int d = 1; d <= kMaxD; ++d) {
          float w = ml / (1.f + fabsf(tau - (float)d));
          float nv = bufr[u][d] + w * hv;
          bufr[u][d - 1] = nv;
          if (d == 1) front = nv;
        }
        bufr[u][kMaxD] = 0.f;
        __hip_bfloat16 hb = __float2bfloat16(front);
        unsigned short bits = *(unsigned short*)&hb;
        pk |= ((unsigned int)bits) << (16 * u);
      }
      __hip_atomic_store((unsigned int*)(h0w + eb * kH + wg * kJPW + eq * 2), pk,
                         __ATOMIC_RELAXED, __HIP_MEMORY_SCOPE_AGENT);
    }

    // ---- fence-free grid barrier ----
    __builtin_amdgcn_s_waitcnt(0);      // each wave drains its own h0 stores
    __syncthreads();
    if (tid == 0)
      __hip_atomic_store(&P.arrive[wg * 16], t + 1,
                         __ATOMIC_RELAXED, __HIP_MEMORY_SCOPE_AGENT);
    if (tid < kNWG) {
      while (__hip_atomic_load(&P.arrive[tid * 16],
                               __ATOMIC_RELAXED, __HIP_MEMORY_SCOPE_AGENT) < t + 1)
        __builtin_amdgcn_s_sleep(1);
    }
    __syncthreads();
    asm volatile("" ::: "memory");
  }
}

extern "C" void kernel_launch(void* const* d_in, const int* in_sizes, int n_in,
                              void* d_out, int out_size, void* d_ws, size_t ws_size,
                              hipStream_t stream) {
  const float* x      = (const float*)d_in[0];
  const int*   lens   = (const int*)d_in[1];
  const float* W_in   = (const float*)d_in[3];
  const float* b_in   = (const float*)d_in[4];
  const float* W_pass = (const float*)d_in[5];
  const float* b_pass = (const float*)d_in[6];
  const float* W_tau  = (const float*)d_in[7];
  const float* b_tau  = (const float*)d_in[8];
  const float* W_mem  = (const float*)d_in[9];
  const float* b_mem  = (const float*)d_in[10];
  const float* W_out  = (const float*)d_in[11];
  const float* b_out  = (const float*)d_in[12];

  char* ws = (char*)d_ws;
  size_t off = 0;
  int* arrive = (int*)(ws + off);                 off += 2048;
  __hip_bfloat16* h0a = (__hip_bfloat16*)(ws + off); off += (size_t)kB * kH * 2;
  __hip_bfloat16* h0b = (__hip_bfloat16*)(ws + off); off += (size_t)kB * kH * 2;
  float* bias = (float*)(ws + off);               off += 6 * kH * sizeof(float);
  __hip_bfloat16* WtOut = (__hip_bfloat16*)(ws + off); off += (size_t)kC * kH * 2;
  __hip_bfloat16* xb    = (__hip_bfloat16*)(ws + off); off += (size_t)kB * kS * kI * 2;
  __hip_bfloat16* Wall  = (__hip_bfloat16*)(ws + off); off += (size_t)6 * kH * kKz * 2;
  __hip_bfloat16* BtP   = (__hip_bfloat16*)(ws + off); off += (size_t)kH * kH * 2;
  __hip_bfloat16* BtT   = (__hip_bfloat16*)(ws + off); off += (size_t)kH * kH * 2;
  __hip_bfloat16* BtM   = (__hip_bfloat16*)(ws + off); off += (size_t)kH * kH * 2;
  __hip_bfloat16* Cip   = (__hip_bfloat16*)(ws + off); off += (size_t)kKz * kH * 2;

  // zero barrier flags + both h0 ping-pong buffers
  hipMemsetAsync(d_ws, 0, 2048 + 2 * (size_t)kB * kH * 2, stream);

  prep_cast<<<512, 256, 0, stream>>>(x, W_in, W_pass, W_tau, W_mem, W_out,
                                     xb, Wall, BtP, BtT, BtM, WtOut);
  prep_bias<<<1, 512, 0, stream>>>(b_in, b_pass, b_tau, b_mem, W_pass, W_tau, W_mem, bias);
  prep_mm1<<<dim3(40, 32, 3), 64, 0, stream>>>(W_in, BtP, BtT, BtM, Wall, Cip);
  prep_mm2<<<dim3(40, 32, 2), 64, 0, stream>>>(Cip, BtT, BtM, Wall);

  KParams P;
  P.xb = xb; P.Wall = Wall; P.WtOut = WtOut; P.bias = bias; P.b_out = b_out;
  P.h0a = h0a; P.h0b = h0b; P.arrive = arrive; P.lengths = lens;
  P.dout = (float*)d_out;

  rnn_main<<<dim3(kNWG), dim3(256), 0, stream>>>(P);
}

// Round 5
// 2550.484 us; speedup vs baseline: 2.6959x; 1.3640x over previous
//
#include <hip/hip_runtime.h>
#include <hip/hip_bf16.h>

// DelayRNN on MI355X — Round 5.
// Barrier-free recurrence: h0 published as tagged words ((t+1)<<16 | bf16bits)
// via 8B agent atomics; consumers poll the DATA (tags) — no flags, no release
// hop, no store-drain-before-flag. Unit-partitioned GEMM (wave owns
// (matrix,batch-half) units, full K) removes duplicated B reads. Decode GEMV
// replaced by h0hist snapshots + one tail GEMM after a single post-loop flag
// barrier. x prefetched in epilogue phase. 2 local syncs per step.

constexpr int kB    = 32;
constexpr int kS    = 256;
constexpr int kI    = 128;
constexpr int kH    = 512;
constexpr int kC    = 64;
constexpr int kOutL = 64;
constexpr int kMaxD = 16;
constexpr int kBufD = 17;
constexpr int kNWG  = 32;
constexpr int kJPW  = 16;
constexpr int kSteps = kS + kOutL;   // 320
constexpr int kKz   = kH + kI;       // 640
constexpr int kZPad = 8;             // zs row stride 648 elem (1296 B)

typedef __bf16 bf16x8 __attribute__((ext_vector_type(8)));
typedef float  f32x4  __attribute__((ext_vector_type(4)));
typedef unsigned int u32x4 __attribute__((ext_vector_type(4)));

__device__ __forceinline__ f32x4 MFMA(bf16x8 a, bf16x8 b, f32x4 c) {
  return __builtin_amdgcn_mfma_f32_16x16x32_bf16(a, b, c, 0, 0, 0);
}
__device__ __forceinline__ bf16x8 ld8(const __hip_bfloat16* p) {
  return *reinterpret_cast<const bf16x8*>(p);
}
__device__ __forceinline__ bf16x8 ld8_f32(const float* p) {
  float4 a = *(const float4*)p, b = *(const float4*)(p + 4);
  union { __hip_bfloat16 h[8]; bf16x8 v; } c;
  c.h[0] = __float2bfloat16(a.x); c.h[1] = __float2bfloat16(a.y);
  c.h[2] = __float2bfloat16(a.z); c.h[3] = __float2bfloat16(a.w);
  c.h[4] = __float2bfloat16(b.x); c.h[5] = __float2bfloat16(b.y);
  c.h[6] = __float2bfloat16(b.z); c.h[7] = __float2bfloat16(b.w);
  return c.v;
}
__device__ __forceinline__ float sigm(float x) { return 1.0f / (1.0f + __expf(-x)); }

// ---------------- prep kernels (unchanged from R4) ----------------

__global__ void prep_cast(const float* x, const float* W_in, const float* W_pass,
                          const float* W_tau, const float* W_mem, const float* W_out,
                          __hip_bfloat16* xb, __hip_bfloat16* Wall, __hip_bfloat16* BtP,
                          __hip_bfloat16* BtT, __hip_bfloat16* BtM, __hip_bfloat16* WtOut) {
  const int tid = blockIdx.x * blockDim.x + threadIdx.x;
  const int nth = gridDim.x * blockDim.x;
  for (int i = tid; i < kB * kS * kI; i += nth) xb[i] = __float2bfloat16(x[i]);
  for (int i = tid; i < kH * kKz; i += nth) {
    int j = i / kKz, k = i - j * kKz;
    Wall[i] = __float2bfloat16(W_in[k * kH + j]);
  }
  for (int i = tid; i < kH * kH; i += nth) {
    int j = i >> 9, k = i & 511;
    BtP[i] = __float2bfloat16(W_pass[k * kH + j]);
    BtT[i] = __float2bfloat16(W_tau[k * kH + j]);
    BtM[i] = __float2bfloat16(W_mem[k * kH + j]);
  }
  for (int i = tid; i < kC * kH; i += nth) {
    int c = i >> 9, k = i & 511;
    WtOut[i] = __float2bfloat16(W_out[k * kC + c]);
  }
}

__global__ void prep_bias(const float* b_in, const float* b_pass, const float* b_tau,
                          const float* b_mem, const float* W_pass, const float* W_tau,
                          const float* W_mem, float* bias) {
  __shared__ float bp_s[kH];
  const int j = threadIdx.x;
  float s1 = 0.f, s2 = 0.f, s3 = 0.f;
  for (int k = 0; k < kH; ++k) {
    float bi = b_in[k];
    s1 += bi * W_pass[k * kH + j];
    s2 += bi * W_tau[k * kH + j];
    s3 += bi * W_mem[k * kH + j];
  }
  float bP = s1 + b_pass[j];
  bias[j]          = b_in[j];
  bias[kH + j]     = bP;
  bias[2 * kH + j] = s2 + b_tau[j];
  bias[4 * kH + j] = s3 + b_mem[j];
  bp_s[j] = bP;
  __syncthreads();
  float s4 = 0.f, s5 = 0.f;
  for (int k = 0; k < kH; ++k) {
    float v = bp_s[k];
    s4 += v * W_tau[k * kH + j];
    s5 += v * W_mem[k * kH + j];
  }
  bias[3 * kH + j] = s4 + b_tau[j];
  bias[5 * kH + j] = s5 + b_mem[j];
}

__global__ __launch_bounds__(64) void prep_mm1(const float* W_in, const __hip_bfloat16* BtP,
    const __hip_bfloat16* BtT, const __hip_bfloat16* BtM,
    __hip_bfloat16* Wall, __hip_bfloat16* Cip) {
  const int bm = blockIdx.x, bn = blockIdx.y, z = blockIdx.z;
  const int lane = threadIdx.x;
  const int kq = (lane >> 4) * 8;
  const __hip_bfloat16* Bt = (z == 0) ? BtP : (z == 1 ? BtT : BtM);
  const int mat = (z == 0) ? 1 : (z == 1 ? 2 : 4);
  const float* arow = W_in + (size_t)(bm * 16 + (lane & 15)) * kH;
  const __hip_bfloat16* brow = Bt + (size_t)(bn * 16 + (lane & 15)) * kH;
  f32x4 acc = {0.f, 0.f, 0.f, 0.f};
  for (int i = 0; i < 16; ++i) {
    const int kk = i * 32 + kq;
    acc = MFMA(ld8_f32(arow + kk), ld8(brow + kk), acc);
  }
  const int rm = (lane >> 4) * 4, cn = lane & 15;
  union { __hip_bfloat16 h[4]; ushort4 s; } cv;
#pragma unroll
  for (int r = 0; r < 4; ++r) cv.h[r] = __float2bfloat16(acc[r]);
  __hip_bfloat16* wd = Wall + ((size_t)mat * kH + bn * 16 + cn) * kKz + bm * 16 + rm;
  *(ushort4*)wd = cv.s;
  if (z == 0) {
#pragma unroll
    for (int r = 0; r < 4; ++r)
      Cip[(size_t)(bm * 16 + rm + r) * kH + bn * 16 + cn] = cv.h[r];
  }
}

__global__ __launch_bounds__(64) void prep_mm2(const __hip_bfloat16* Cip,
    const __hip_bfloat16* BtT, const __hip_bfloat16* BtM, __hip_bfloat16* Wall) {
  const int bm = blockIdx.x, bn = blockIdx.y, z = blockIdx.z;
  const int lane = threadIdx.x;
  const int kq = (lane >> 4) * 8;
  const __hip_bfloat16* Bt = (z == 0) ? BtT : BtM;
  const int mat = (z == 0) ? 3 : 5;
  const __hip_bfloat16* arow = Cip + (size_t)(bm * 16 + (lane & 15)) * kH;
  const __hip_bfloat16* brow = Bt + (size_t)(bn * 16 + (lane & 15)) * kH;
  f32x4 acc = {0.f, 0.f, 0.f, 0.f};
  for (int i = 0; i < 16; ++i) {
    const int kk = i * 32 + kq;
    acc = MFMA(ld8(arow + kk), ld8(brow + kk), acc);
  }
  const int rm = (lane >> 4) * 4, cn = lane & 15;
  union { __hip_bfloat16 h[4]; ushort4 s; } cv;
#pragma unroll
  for (int r = 0; r < 4; ++r) cv.h[r] = __float2bfloat16(acc[r]);
  __hip_bfloat16* wd = Wall + ((size_t)mat * kH + bn * 16 + cn) * kKz + bm * 16 + rm;
  *(ushort4*)wd = cv.s;
}

// ---------------- main persistent kernel ----------------

struct KParams {
  const __hip_bfloat16* xb;       // bf16 input [B][S][I]
  const __hip_bfloat16* Wall;     // [6][512][640] composites, [col][k]
  const __hip_bfloat16* WtOut;    // [64][512]
  const float* bias;              // [6][512]
  const float* b_out;             // [64]
  unsigned* h0a;                  // ping: [32][512] tagged words
  unsigned* h0b;                  // pong
  __hip_bfloat16* h0hist;         // [64][32][512] decode-entry h0 snapshots
  int* arrive;                    // 32 flags, 64B stride (tail barrier only)
  const int* lengths;
  float* dout;                    // [B][kOutL][C]
};

__global__ __launch_bounds__(256, 1) void rnn_main(KParams P) {
  __shared__ __align__(16) __hip_bfloat16 zs[kB][kKz + kZPad];  // 41,472 B
  __shared__ float outLDS[6][kB][kJPW + 1];                     // 13,056 B
  __shared__ int   len_s[kB];

  const int wg = blockIdx.x, tid = threadIdx.x;
  const int lane = tid & 63, wave = tid >> 6;
  const int kq = (lane >> 4) * 8;
  const int jn = wg * kJPW + (lane & 15);
  // unit partition: wave w owns units {3w,3w+1,3w+2}, unit u = (mat=u>>1, half=u&1)
  const int u0m = (3 * wave) >> 1, u2m = (3 * wave + 2) >> 1;
  const __hip_bfloat16* WbA = P.Wall + ((size_t)u0m * kH + jn) * kKz;
  const __hip_bfloat16* WbC = P.Wall + ((size_t)u2m * kH + jn) * kKz;
  const bool wodd = wave & 1;
  const int eb = tid >> 3, eq = tid & 7;      // epilogue: batch, col-pair
  const int xrow = tid >> 3, xch = tid & 7;   // x staging geometry

  float bufr[2][kBufD];
#pragma unroll
  for (int u = 0; u < 2; ++u)
#pragma unroll
    for (int d = 0; d < kBufD; ++d) bufr[u][d] = 0.f;

  if (tid < kB) len_s[tid] = P.lengths[tid];

  // stage x(0)
  {
#pragma unroll
    for (int i = 0; i < 2; ++i) {
      const int c2 = i * 8 + xch;
      const u32x4 xv = *(const u32x4*)(P.xb + ((size_t)xrow * kS + 0) * kI + c2 * 8);
      *(u32x4*)&zs[xrow][kH + c2 * 8] = xv;
    }
  }

  const unsigned o0 = tid * 16u;

  for (int t = 0; t < kSteps; ++t) {
    const unsigned* h0r = (t & 1) ? P.h0b : P.h0a;
    unsigned*       h0w = (t & 1) ? P.h0a : P.h0b;

    // ---- stage h0: poll tagged words until all tags == t, then unpack ----
    {
      const unsigned tga = ((unsigned)t) << 16;
      u32x4 c0, c1, c2, c3, c4, c5, c6, c7, c8, c9, cA, cB, cC, cD, cE, cF;
      for (;;) {
        asm volatile(
            "global_load_dwordx4 %0, %16, %32 sc0 sc1\n\t"
            "global_load_dwordx4 %1, %17, %32 sc0 sc1\n\t"
            "global_load_dwordx4 %2, %18, %32 sc0 sc1\n\t"
            "global_load_dwordx4 %3, %19, %32 sc0 sc1\n\t"
            "global_load_dwordx4 %4, %20, %32 sc0 sc1\n\t"
            "global_load_dwordx4 %5, %21, %32 sc0 sc1\n\t"
            "global_load_dwordx4 %6, %22, %32 sc0 sc1\n\t"
            "global_load_dwordx4 %7, %23, %32 sc0 sc1\n\t"
            "global_load_dwordx4 %8, %24, %32 sc0 sc1\n\t"
            "global_load_dwordx4 %9, %25, %32 sc0 sc1\n\t"
            "global_load_dwordx4 %10, %26, %32 sc0 sc1\n\t"
            "global_load_dwordx4 %11, %27, %32 sc0 sc1\n\t"
            "global_load_dwordx4 %12, %28, %32 sc0 sc1\n\t"
            "global_load_dwordx4 %13, %29, %32 sc0 sc1\n\t"
            "global_load_dwordx4 %14, %30, %32 sc0 sc1\n\t"
            "global_load_dwordx4 %15, %31, %32 sc0 sc1\n\t"
            "s_waitcnt vmcnt(0)"
            : "=&v"(c0), "=&v"(c1), "=&v"(c2), "=&v"(c3),
              "=&v"(c4), "=&v"(c5), "=&v"(c6), "=&v"(c7),
              "=&v"(c8), "=&v"(c9), "=&v"(cA), "=&v"(cB),
              "=&v"(cC), "=&v"(cD), "=&v"(cE), "=&v"(cF)
            : "v"(o0), "v"(o0 + 4096u), "v"(o0 + 8192u), "v"(o0 + 12288u),
              "v"(o0 + 16384u), "v"(o0 + 20480u), "v"(o0 + 24576u), "v"(o0 + 28672u),
              "v"(o0 + 32768u), "v"(o0 + 36864u), "v"(o0 + 40960u), "v"(o0 + 45056u),
              "v"(o0 + 49152u), "v"(o0 + 53248u), "v"(o0 + 57344u), "v"(o0 + 61440u),
              "s"(h0r)
            : "memory");
        // 8B atomic publish => tags within each 8B pair identical: check .x/.z only
        unsigned bad =
            (c0.x ^ tga) | (c0.z ^ tga) | (c1.x ^ tga) | (c1.z ^ tga) |
            (c2.x ^ tga) | (c2.z ^ tga) | (c3.x ^ tga) | (c3.z ^ tga) |
            (c4.x ^ tga) | (c4.z ^ tga) | (c5.x ^ tga) | (c5.z ^ tga) |
            (c6.x ^ tga) | (c6.z ^ tga) | (c7.x ^ tga) | (c7.z ^ tga) |
            (c8.x ^ tga) | (c8.z ^ tga) | (c9.x ^ tga) | (c9.z ^ tga) |
            (cA.x ^ tga) | (cA.z ^ tga) | (cB.x ^ tga) | (cB.z ^ tga) |
            (cC.x ^ tga) | (cC.z ^ tga) | (cD.x ^ tga) | (cD.z ^ tga) |
            (cE.x ^ tga) | (cE.z ^ tga) | (cF.x ^ tga) | (cF.z ^ tga);
        if ((bad >> 16) == 0) break;
        __builtin_amdgcn_s_sleep(2);
      }
#define UNP(ci, idx)                                                         \
  { const unsigned ch = (idx)*256u + (unsigned)tid;                          \
    *(uint2*)&zs[ch >> 7][(ch & 127u) * 4] =                                 \
        make_uint2((ci.x & 0xffffu) | (ci.y << 16),                          \
                   (ci.z & 0xffffu) | (ci.w << 16)); }
      UNP(c0, 0)  UNP(c1, 1)  UNP(c2, 2)  UNP(c3, 3)
      UNP(c4, 4)  UNP(c5, 5)  UNP(c6, 6)  UNP(c7, 7)
      UNP(c8, 8)  UNP(c9, 9)  UNP(cA, 10) UNP(cB, 11)
      UNP(cC, 12) UNP(cD, 13) UNP(cE, 14) UNP(cF, 15)
#undef UNP
    }
    __syncthreads();

    // ---- unit-partitioned GEMM: 3 units/wave, full K=640, no dup B reads ----
    {
      f32x4 A0 = {0.f,0.f,0.f,0.f}, A1 = {0.f,0.f,0.f,0.f}, A2 = {0.f,0.f,0.f,0.f};
      const int rlo = lane & 15, rhi = 16 + (lane & 15);
      if (!wodd) {
        // units: (u0m,h0),(u0m,h1),(u2m,h0)
#pragma unroll
        for (int i = 0; i < 20; ++i) {
          const int kk = i * 32 + kq;
          bf16x8 alo = *(const bf16x8*)&zs[rlo][kk];
          bf16x8 ahi = *(const bf16x8*)&zs[rhi][kk];
          bf16x8 b0 = ld8(WbA + kk), b2 = ld8(WbC + kk);
          A0 = MFMA(alo, b0, A0);
          A1 = MFMA(ahi, b0, A1);
          A2 = MFMA(alo, b2, A2);
        }
      } else {
        // units: (u0m,h1),(u2m,h0),(u2m,h1)
#pragma unroll
        for (int i = 0; i < 20; ++i) {
          const int kk = i * 32 + kq;
          bf16x8 alo = *(const bf16x8*)&zs[rlo][kk];
          bf16x8 ahi = *(const bf16x8*)&zs[rhi][kk];
          bf16x8 b0 = ld8(WbA + kk), b2 = ld8(WbC + kk);
          A0 = MFMA(ahi, b0, A0);
          A1 = MFMA(alo, b2, A1);
          A2 = MFMA(ahi, b2, A2);
        }
      }
      f32x4 acc[3] = {A0, A1, A2};
#pragma unroll
      for (int s = 0; s < 3; ++s) {
        const int u = 3 * wave + s;
        const int m = u >> 1, rb = (u & 1) * 16;
#pragma unroll
        for (int r = 0; r < 4; ++r)
          outLDS[m][rb + (lane >> 4) * 4 + r][lane & 15] = acc[s][r];
      }
    }
    __syncthreads();

    // ---- epilogue: blend, gates, delay buffer, tagged publish, x prefetch ----
    {
      const bool msk = (t >= kS) || (t < len_s[eb]);
      unsigned short bits[2];
#pragma unroll
      for (int u = 0; u < 2; ++u) {
        const int jl = eq * 2 + u, j = wg * kJPW + jl;
        float hp = outLDS[0][eb][jl] + P.bias[j];
        float pv = outLDS[1][eb][jl] + P.bias[kH + j];
        float ta = outLDS[2][eb][jl] + P.bias[2 * kH + j];
        float tb = outLDS[3][eb][jl] + P.bias[3 * kH + j];
        float ma = outLDS[4][eb][jl] + P.bias[4 * kH + j];
        float mb = outLDS[5][eb][jl] + P.bias[5 * kH + j];
        float hv = msk ? pv : hp;
        float gt = msk ? tb : ta;
        float gm = msk ? mb : ma;
        float tau = 16.f * sigm(gt);
        tau = fminf(fmaxf(tau, 1.f), 16.f);
        float ml = sigm(gm);
        float front = 0.f;
#pragma unroll
        for (int d = 1; d <= kMaxD; ++d) {
          float w = ml / (1.f + fabsf(tau - (float)d));
          float nv = bufr[u][d] + w * hv;
          bufr[u][d - 1] = nv;
          if (d == 1) front = nv;
        }
        bufr[u][kMaxD] = 0.f;
        __hip_bfloat16 hb = __float2bfloat16(front);
        unsigned short bt;
        __builtin_memcpy(&bt, &hb, 2);
        bits[u] = bt;
      }
      const unsigned tagp = ((unsigned)(t + 1)) << 16;
      const unsigned lo = tagp | bits[0], hi = tagp | bits[1];
      const unsigned long long pk = ((unsigned long long)hi << 32) | lo;
      __hip_atomic_store((unsigned long long*)(h0w + eb * kH + wg * kJPW + eq * 2),
                         pk, __ATOMIC_RELAXED, __HIP_MEMORY_SCOPE_AGENT);

      // decode-entry snapshot: h0 at entry of step t+1 (needed for t+1 >= kS)
      if ((unsigned)(t - (kS - 1)) < (unsigned)kOutL) {
        const unsigned hv = ((unsigned)bits[1] << 16) | bits[0];
        unsigned* hp = (unsigned*)(P.h0hist + ((size_t)(t - (kS - 1)) * kB + eb) * kH)
                       + (wg * 8 + eq);
        __hip_atomic_store(hp, hv, __ATOMIC_RELAXED, __HIP_MEMORY_SCOPE_AGENT);
      }

      // prefetch x(t+1) into zs (zs h0-region is rewritten next staging; x region
      // untouched there; GEMM(t+1) reads after the staging syncthreads)
      const int tn = t + 1;
      if (tn < kS) {
#pragma unroll
        for (int i = 0; i < 2; ++i) {
          const int c2 = i * 8 + xch;
          const u32x4 xv = *(const u32x4*)(P.xb + ((size_t)xrow * kS + tn) * kI + c2 * 8);
          *(u32x4*)&zs[xrow][kH + c2 * 8] = xv;
        }
      } else if (tn == kS) {
        const u32x4 zv = {0u, 0u, 0u, 0u};
#pragma unroll
        for (int i = 0; i < 2; ++i) {
          const int c2 = i * 8 + xch;
          *(u32x4*)&zs[xrow][kH + c2 * 8] = zv;
        }
      }
    }
    // no grid barrier, no end-of-step syncthreads: next staging writes only the
    // zs h0-region and its own global words; dataflow tags order everything.
  }

  // ---- one post-loop grid barrier, then tail GEMM for all decode outputs ----
  __builtin_amdgcn_s_waitcnt(0);
  __syncthreads();
  if (tid == 0)
    __hip_atomic_store(&P.arrive[wg * 16], 1, __ATOMIC_RELAXED, __HIP_MEMORY_SCOPE_AGENT);
  if (tid < kNWG) {
    while (__hip_atomic_load(&P.arrive[tid * 16],
                             __ATOMIC_RELAXED, __HIP_MEMORY_SCOPE_AGENT) < 1)
      __builtin_amdgcn_s_sleep(2);
  }
  __syncthreads();

  // dout[b][td][c] = h0hist[td][b][:] @ WtOut[c][:] + b_out[c]
  {
    const int mrow = wg * 64 + wave * 16 + (lane & 15);  // m = td*32 + b
    const char* ap = (const char*)P.h0hist + (size_t)mrow * 1024 + (lane >> 4) * 16;
    u32x4 d0, d1, d2, d3, d4, d5, d6, d7, d8, d9, dA, dB, dC, dD, dE, dF;
    asm volatile(
        "global_load_dwordx4 %0, %16, off sc0 sc1\n\t"
        "global_load_dwordx4 %1, %16, off offset:64 sc0 sc1\n\t"
        "global_load_dwordx4 %2, %16, off offset:128 sc0 sc1\n\t"
        "global_load_dwordx4 %3, %16, off offset:192 sc0 sc1\n\t"
        "global_load_dwordx4 %4, %16, off offset:256 sc0 sc1\n\t"
        "global_load_dwordx4 %5, %16, off offset:320 sc0 sc1\n\t"
        "global_load_dwordx4 %6, %16, off offset:384 sc0 sc1\n\t"
        "global_load_dwordx4 %7, %16, off offset:448 sc0 sc1\n\t"
        "global_load_dwordx4 %8, %16, off offset:512 sc0 sc1\n\t"
        "global_load_dwordx4 %9, %16, off offset:576 sc0 sc1\n\t"
        "global_load_dwordx4 %10, %16, off offset:640 sc0 sc1\n\t"
        "global_load_dwordx4 %11, %16, off offset:704 sc0 sc1\n\t"
        "global_load_dwordx4 %12, %16, off offset:768 sc0 sc1\n\t"
        "global_load_dwordx4 %13, %16, off offset:832 sc0 sc1\n\t"
        "global_load_dwordx4 %14, %16, off offset:896 sc0 sc1\n\t"
        "global_load_dwordx4 %15, %16, off offset:960 sc0 sc1\n\t"
        "s_waitcnt vmcnt(0)"
        : "=&v"(d0), "=&v"(d1), "=&v"(d2), "=&v"(d3),
          "=&v"(d4), "=&v"(d5), "=&v"(d6), "=&v"(d7),
          "=&v"(d8), "=&v"(d9), "=&v"(dA), "=&v"(dB),
          "=&v"(dC), "=&v"(dD), "=&v"(dE), "=&v"(dF)
        : "v"(ap)
        : "memory");
    union { u32x4 u; bf16x8 v; } av[16] = {{d0},{d1},{d2},{d3},{d4},{d5},{d6},{d7},
                                           {d8},{d9},{dA},{dB},{dC},{dD},{dE},{dF}};
    f32x4 T0 = {0.f,0.f,0.f,0.f}, T1 = {0.f,0.f,0.f,0.f};
    f32x4 T2 = {0.f,0.f,0.f,0.f}, T3 = {0.f,0.f,0.f,0.f};
#pragma unroll
    for (int ik = 0; ik < 16; ++ik) {
      const int kk = ik * 32 + kq;
      const __hip_bfloat16* wb = P.WtOut + (size_t)(lane & 15) * kH + kk;
      T0 = MFMA(av[ik].v, ld8(wb), T0);
      T1 = MFMA(av[ik].v, ld8(wb + 16 * kH), T1);
      T2 = MFMA(av[ik].v, ld8(wb + 32 * kH), T2);
      T3 = MFMA(av[ik].v, ld8(wb + 48 * kH), T3);
    }
    f32x4 T[4] = {T0, T1, T2, T3};
#pragma unroll
    for (int ct = 0; ct < 4; ++ct) {
      const int c = ct * 16 + (lane & 15);
      const float bo = P.b_out[c];
#pragma unroll
      for (int r = 0; r < 4; ++r) {
        const int m = wg * 64 + wave * 16 + (lane >> 4) * 4 + r;
        const int b = m & 31, td = m >> 5;
        P.dout[(size_t)b * (kOutL * kC) + td * kC + c] = T[ct][r] + bo;
      }
    }
  }
}

extern "C" void kernel_launch(void* const* d_in, const int* in_sizes, int n_in,
                              void* d_out, int out_size, void* d_ws, size_t ws_size,
                              hipStream_t stream) {
  const float* x      = (const float*)d_in[0];
  const int*   lens   = (const int*)d_in[1];
  const float* W_in   = (const float*)d_in[3];
  const float* b_in   = (const float*)d_in[4];
  const float* W_pass = (const float*)d_in[5];
  const float* b_pass = (const float*)d_in[6];
  const float* W_tau  = (const float*)d_in[7];
  const float* b_tau  = (const float*)d_in[8];
  const float* W_mem  = (const float*)d_in[9];
  const float* b_mem  = (const float*)d_in[10];
  const float* W_out  = (const float*)d_in[11];
  const float* b_out  = (const float*)d_in[12];

  char* ws = (char*)d_ws;
  size_t off = 0;
  int* arrive = (int*)(ws + off);                  off += 2048;
  unsigned* h0a = (unsigned*)(ws + off);           off += (size_t)kB * kH * 4;   // 64KB
  unsigned* h0b = (unsigned*)(ws + off);           off += (size_t)kB * kH * 4;   // 64KB
  float* bias = (float*)(ws + off);                off += 6 * kH * sizeof(float);
  __hip_bfloat16* WtOut = (__hip_bfloat16*)(ws + off); off += (size_t)kC * kH * 2;
  __hip_bfloat16* h0hist = (__hip_bfloat16*)(ws + off); off += (size_t)kOutL * kB * kH * 2; // 2MB
  __hip_bfloat16* xb    = (__hip_bfloat16*)(ws + off); off += (size_t)kB * kS * kI * 2;
  __hip_bfloat16* Wall  = (__hip_bfloat16*)(ws + off); off += (size_t)6 * kH * kKz * 2;
  __hip_bfloat16* BtP   = (__hip_bfloat16*)(ws + off); off += (size_t)kH * kH * 2;
  __hip_bfloat16* BtT   = (__hip_bfloat16*)(ws + off); off += (size_t)kH * kH * 2;
  __hip_bfloat16* BtM   = (__hip_bfloat16*)(ws + off); off += (size_t)kH * kH * 2;
  __hip_bfloat16* Cip   = (__hip_bfloat16*)(ws + off); off += (size_t)kKz * kH * 2;

  // zero barrier flags + both tagged h0 buffers (tag 0 == step-0 expectation)
  hipMemsetAsync(d_ws, 0, 2048 + 2 * (size_t)kB * kH * 4, stream);

  prep_cast<<<512, 256, 0, stream>>>(x, W_in, W_pass, W_tau, W_mem, W_out,
                                     xb, Wall, BtP, BtT, BtM, WtOut);
  prep_bias<<<1, 512, 0, stream>>>(b_in, b_pass, b_tau, b_mem, W_pass, W_tau, W_mem, bias);
  prep_mm1<<<dim3(40, 32, 3), 64, 0, stream>>>(W_in, BtP, BtT, BtM, Wall, Cip);
  prep_mm2<<<dim3(40, 32, 2), 64, 0, stream>>>(Cip, BtT, BtM, Wall);

  KParams P;
  P.xb = xb; P.Wall = Wall; P.WtOut = WtOut; P.bias = bias; P.b_out = b_out;
  P.h0a = h0a; P.h0b = h0b; P.h0hist = h0hist; P.arrive = arrive;
  P.lengths = lens; P.dout = (float*)d_out;

  rnn_main<<<dim3(kNWG), dim3(256), 0, stream>>>(P);
}